// Round 8
// baseline (340.935 us; speedup 1.0000x reference)
//
#include <hip/hip_runtime.h>
#include <hip/hip_bf16.h>
#include <stdint.h>

typedef __bf16 bf16;
typedef __bf16 bf16x4 __attribute__((ext_vector_type(4)));
typedef __bf16 bf16x8 __attribute__((ext_vector_type(8)));
typedef float f32x4 __attribute__((ext_vector_type(4)));
typedef float f32x8 __attribute__((ext_vector_type(8)));

#define MFMA16 __builtin_amdgcn_mfma_f32_16x16x32_bf16

// async global->LDS, 16B per lane; LDS dest must be base + lane*16 pattern.
__device__ __forceinline__ void gload_lds16(void* lds, const void* g) {
  __builtin_amdgcn_global_load_lds(
      (const __attribute__((address_space(1))) unsigned int*)g,
      (__attribute__((address_space(3))) unsigned int*)lds, 16, 0, 0);
}

// ---------------------------------------------------------------------------
// fp32 -> bf16 weight convert (HBM-bound, ~4 us)
// ---------------------------------------------------------------------------
__global__ __launch_bounds__(256) void cvt4(const float* __restrict__ w0,
                                            const float* __restrict__ w1,
                                            const float* __restrict__ w2,
                                            const float* __restrict__ w3,
                                            bf16* __restrict__ dst) {
  const float* srcs[4] = {w0, w1, w2, w3};
  const float* src = srcs[blockIdx.y];
  int i = (blockIdx.x * 256 + threadIdx.x) * 4;
  f32x4 v = *(const f32x4*)(src + i);
  bf16x4 o;
#pragma unroll
  for (int j = 0; j < 4; j++) o[j] = (bf16)v[j];
  *(bf16x4*)(dst + (size_t)blockIdx.y * 1048576 + i) = o;
}

// ---------------------------------------------------------------------------
// Strip-interleaved XCD remap. Linear id -> XCD via id%8 (round-robin).
// m-strip index === xcd (mod 8): every XCD gets strips {x, 8+x, 16+x, ...}
// = one s-low and one s-high strip per batch -> vl-skip load balanced by
// construction, while all n-blocks of a strip stay on one XCD (L2 locality:
// A strip + W working set ~4MB = per-XCD L2). Perf heuristic only.
// ---------------------------------------------------------------------------
__device__ __forceinline__ void remap8(int& m0, int& n0) {  // grid (8,64)
  int id = blockIdx.y * 8 + blockIdx.x;
  int xcd = id & 7;
  int j = id >> 3;                    // 0..63
  m0 = ((j >> 3) * 8 + xcd) * 128;    // consecutive j sweep n within strip
  n0 = (j & 7) * 128;
}

__device__ __forceinline__ void remap16(int& m0, int& n0) {  // grid (16,64)
  int id = blockIdx.y * 16 + blockIdx.x;
  int xcd = id & 7;
  int j = id >> 3;                    // 0..127
  m0 = ((j >> 4) * 8 + xcd) * 128;
  n0 = (j & 15) * 64;
}

// ---------------------------------------------------------------------------
// Fused Q/K/V projections, fp32 A staged directly (no separate convert).
// A tile rows are 128B = 8 x 16B chunks; chunk c stored at slot c^(row&7)
// (XOR applied to the GLOBAL column so the LDS side stays base+lane*16).
// Fragment read un-XORs and converts fp32->bf16 (RNE, matches cvt kernel).
// K/V blocks with whole s-strip >= vl skip (their rows are multiplied by
// P==0 in attn -> exact 0 regardless of content).
// ---------------------------------------------------------------------------
__global__ __launch_bounds__(256) void gemm_qkv(
    const float* __restrict__ q, const float* __restrict__ k,
    const float* __restrict__ v, const bf16* __restrict__ wb,
    const int* __restrict__ vlen, bf16* __restrict__ qp,
    bf16* __restrict__ kp, bf16* __restrict__ vt) {
  __shared__ float Asf[128 * 32];
  __shared__ bf16 Bs[128 * 32];
  int m0, n0;
  remap8(m0, n0);
  const int z = blockIdx.z;
  if (z >= 1) {
    int b = m0 >> 11, s0 = m0 & 2047, vl = vlen[b];
    if (vl != 0 && s0 >= vl) return;
  }
  const float* A = (z == 0) ? q : (z == 1) ? k : v;
  const bf16* W = wb + (size_t)z * 1048576;
  bf16* C = (z == 0) ? qp : (z == 1) ? kp : vt;
  const int mode = (z == 2) ? 2 : 1;

  const int t = threadIdx.x;
  const int lane = t & 63;
  const int quad = lane >> 4;
  const int m16 = lane & 15;
  const int w = t >> 6;
  const int wm = (w >> 1) * 64;
  const int wn = (w & 1) * 64;

  f32x4 acc[4][4];
#pragma unroll
  for (int i = 0; i < 4; i++)
#pragma unroll
    for (int j = 0; j < 4; j++) acc[i][j] = (f32x4){0.f, 0.f, 0.f, 0.f};

  for (int kt = 0; kt < 32; kt++) {
    __syncthreads();  // prior readers done
#pragma unroll
    for (int p = 0; p < 4; p++) {  // A: 1024 16B-chunks (4 floats each)
      int idx = p * 256 + t;
      int row = idx >> 3;
      int gc = (idx & 7) ^ (row & 7);  // XOR swizzle in global address
      gload_lds16(&Asf[idx * 4],
                  A + (size_t)(m0 + row) * 1024 + kt * 32 + gc * 4);
    }
#pragma unroll
    for (int p = 0; p < 2; p++) {  // B: 512 chunks, m97 layout (64B rows)
      int idx = p * 256 + t;
      int row = idx >> 2;
      int ce = (idx & 3) * 8;
      gload_lds16(&Bs[idx * 8],
                  W + (size_t)(n0 + row) * 1024 + kt * 32 + ce);
    }
    __syncthreads();  // barrier drains vmcnt: staged data visible

    bf16x8 af[4], bfr[4];
#pragma unroll
    for (int i = 0; i < 4; i++) {
      int rr = wm + i * 16 + m16;
      int e = rr & 7;
      f32x4 lo = *(const f32x4*)&Asf[rr * 32 + (((2 * quad) ^ e) * 4)];
      f32x4 hi = *(const f32x4*)&Asf[rr * 32 + (((2 * quad + 1) ^ e) * 4)];
      bf16x8 a8;
#pragma unroll
      for (int j = 0; j < 4; j++) {
        a8[j] = (bf16)lo[j];
        a8[4 + j] = (bf16)hi[j];
      }
      af[i] = a8;
      bfr[i] = *(const bf16x8*)&Bs[(wn + i * 16 + m16) * 32 + quad * 8];
    }
#pragma unroll
    for (int i = 0; i < 4; i++)
#pragma unroll
      for (int j = 0; j < 4; j++)
        acc[i][j] = MFMA16(af[i], bfr[j], acc[i][j], 0, 0, 0);
  }

#pragma unroll
  for (int i = 0; i < 4; i++) {
    int rbase = m0 + wm + i * 16 + quad * 4;
#pragma unroll
    for (int j = 0; j < 4; j++) {
      int col = n0 + wn + j * 16 + m16;
#pragma unroll
      for (int r = 0; r < 4; r++) {
        int row = rbase + r;
        int b = row >> 11, s = row & 2047;
        int h = col >> 6, d = col & 63;
        bf16 val = (bf16)acc[i][j][r];
        if (mode == 1)
          C[(((size_t)(b * 16 + h)) * 2048 + s) * 64 + d] = val;
        else
          C[(((size_t)(b * 16 + h)) * 64 + d) * 2048 + s] = val;
      }
    }
  }
}

// ---------------------------------------------------------------------------
// Output projection: 128x64 tiles, grid (16,64) = 1024 blocks = 4/CU.
// A (ctx) bf16, W bf16 (pre-converted), C fp32 = d_out.
// ---------------------------------------------------------------------------
__global__ __launch_bounds__(256) void gemm_out(const bf16* __restrict__ A,
                                                const bf16* __restrict__ W,
                                                float* __restrict__ C) {
  __shared__ bf16 As[128 * 32];
  __shared__ bf16 Bs[64 * 32];
  int m0, n0;
  remap16(m0, n0);

  const int t = threadIdx.x;
  const int lane = t & 63;
  const int quad = lane >> 4;
  const int m16 = lane & 15;
  const int w = t >> 6;
  const int wm = (w >> 1) * 64;
  const int wn = (w & 1) * 32;

  f32x4 acc[4][2];
#pragma unroll
  for (int i = 0; i < 4; i++)
#pragma unroll
    for (int j = 0; j < 2; j++) acc[i][j] = (f32x4){0.f, 0.f, 0.f, 0.f};

  for (int kt = 0; kt < 32; kt++) {
    __syncthreads();
#pragma unroll
    for (int p = 0; p < 2; p++) {  // A: 512 chunks
      int idx = p * 256 + t;
      int row = idx >> 2;
      int ce = (idx & 3) * 8;
      gload_lds16(&As[idx * 8],
                  A + (size_t)(m0 + row) * 1024 + kt * 32 + ce);
    }
    {  // B: 256 chunks
      int idx = t;
      int row = idx >> 2;
      int ce = (idx & 3) * 8;
      gload_lds16(&Bs[idx * 8],
                  W + (size_t)(n0 + row) * 1024 + kt * 32 + ce);
    }
    __syncthreads();

    bf16x8 af[4], bfr[2];
#pragma unroll
    for (int i = 0; i < 4; i++)
      af[i] = *(const bf16x8*)&As[(wm + i * 16 + m16) * 32 + quad * 8];
#pragma unroll
    for (int j = 0; j < 2; j++)
      bfr[j] = *(const bf16x8*)&Bs[(wn + j * 16 + m16) * 32 + quad * 8];
#pragma unroll
    for (int i = 0; i < 4; i++)
#pragma unroll
      for (int j = 0; j < 2; j++)
        acc[i][j] = MFMA16(af[i], bfr[j], acc[i][j], 0, 0, 0);
  }

#pragma unroll
  for (int i = 0; i < 4; i++) {
    int rbase = m0 + wm + i * 16 + quad * 4;
#pragma unroll
    for (int j = 0; j < 2; j++) {
      int col = n0 + wn + j * 16 + m16;
#pragma unroll
      for (int r = 0; r < 4; r++)
        C[(size_t)(rbase + r) * 1024 + col] = acc[i][j][r];
    }
  }
}

// ---------------------------------------------------------------------------
// Fallback GEMM (Tier C): fp32 operands converted in register staging.
// ---------------------------------------------------------------------------
template <int AF32, int WF32>
__global__ __launch_bounds__(256) void gemm_bt(const void* __restrict__ Araw,
                                               const void* __restrict__ Wraw,
                                               void* __restrict__ Craw,
                                               int mode) {
  constexpr int K = 1024;
  __shared__ bf16 As[128 * 32];
  __shared__ bf16 Bs[128 * 32];
  const int t = threadIdx.x;
  const int lane = t & 63;
  const int quad = lane >> 4;
  const int m16 = lane & 15;
  const int w = t >> 6;
  const int m0 = blockIdx.y * 128;
  const int n0 = blockIdx.x * 128;
  const int wm = (w >> 1) * 64;
  const int wn = (w & 1) * 64;

  f32x4 acc[4][4];
#pragma unroll
  for (int i = 0; i < 4; i++)
#pragma unroll
    for (int j = 0; j < 4; j++) acc[i][j] = (f32x4){0.f, 0.f, 0.f, 0.f};

  for (int kt = 0; kt < K / 32; kt++) {
    bf16x8 aR[2], bR[2];
#pragma unroll
    for (int p = 0; p < 2; p++) {
      int idx = p * 256 + t;
      int row = idx >> 2;
      int ce = (idx & 3) * 8;
      size_t aoff = (size_t)(m0 + row) * K + kt * 32 + ce;
      size_t boff = (size_t)(n0 + row) * K + kt * 32 + ce;
      if constexpr (AF32) {
        f32x8 av = *(const f32x8*)((const float*)Araw + aoff);
#pragma unroll
        for (int j = 0; j < 8; j++) aR[p][j] = (bf16)av[j];
      } else {
        aR[p] = *(const bf16x8*)((const bf16*)Araw + aoff);
      }
      if constexpr (WF32) {
        f32x8 bv = *(const f32x8*)((const float*)Wraw + boff);
#pragma unroll
        for (int j = 0; j < 8; j++) bR[p][j] = (bf16)bv[j];
      } else {
        bR[p] = *(const bf16x8*)((const bf16*)Wraw + boff);
      }
    }
    __syncthreads();
#pragma unroll
    for (int p = 0; p < 2; p++) {
      int idx = p * 256 + t;
      *(bf16x8*)&As[idx * 8] = aR[p];
      *(bf16x8*)&Bs[idx * 8] = bR[p];
    }
    __syncthreads();

    bf16x8 af[4], bfr[4];
#pragma unroll
    for (int i = 0; i < 4; i++) {
      af[i] = *(const bf16x8*)&As[(wm + i * 16 + m16) * 32 + quad * 8];
      bfr[i] = *(const bf16x8*)&Bs[(wn + i * 16 + m16) * 32 + quad * 8];
    }
#pragma unroll
    for (int i = 0; i < 4; i++)
#pragma unroll
      for (int j = 0; j < 4; j++)
        acc[i][j] = MFMA16(af[i], bfr[j], acc[i][j], 0, 0, 0);
  }

#pragma unroll
  for (int i = 0; i < 4; i++) {
    int rbase = m0 + wm + i * 16 + quad * 4;
#pragma unroll
    for (int j = 0; j < 4; j++) {
      int col = n0 + wn + j * 16 + m16;
#pragma unroll
      for (int r = 0; r < 4; r++) {
        int row = rbase + r;
        if (mode == 0) {
          ((float*)Craw)[(size_t)row * 1024 + col] = acc[i][j][r];
        } else {
          int b = row >> 11, s = row & 2047;
          int h = col >> 6, d = col & 63;
          bf16 v = (bf16)acc[i][j][r];
          if (mode == 1)
            ((bf16*)Craw)[(((size_t)(b * 16 + h)) * 2048 + s) * 64 + d] = v;
          else
            ((bf16*)Craw)[(((size_t)(b * 16 + h)) * 64 + d) * 2048 + s] = v;
        }
      }
    }
  }
}

// ---------------------------------------------------------------------------
// Flash attention, de-onlined softmax (fixed offset M=32):
//   p = exp(dot*0.125 - 32) = exp2(dot*0.18033688 - 46.166241)
// Masked keys: p = 0 exactly; vl==0: p = 1 (uniform softmax, matches ref).
// Wave owns 32 q-rows (2 A-frags). Grid (S/128, B*H), 256 thr.
// qp/kp: [B,H,S,64]. vt: [B,H,64,S].
// K/V staged via global_load_lds with XOR chunk swizzle (global-side).
// Ps: per-wave 32x64 P tile, row stride 72 elems (2-way banks = free).
// ---------------------------------------------------------------------------
__global__ __launch_bounds__(256) void attn(const bf16* __restrict__ qp,
                                            const bf16* __restrict__ kp,
                                            const bf16* __restrict__ vt,
                                            const int* __restrict__ vlen,
                                            bf16* __restrict__ ctx) {
  __shared__ bf16 Ks[64 * 64];
  __shared__ bf16 Vs[64 * 64];
  __shared__ bf16 Ps[4 * 32 * 72];

  const int t = threadIdx.x;
  const int lane = t & 63;
  const int quad = lane >> 4;
  const int m16 = lane & 15;
  const int sw = m16 & 7;  // read-side XOR (row&7)
  const int w = t >> 6;
  const int bh = blockIdx.y;
  const int qt = blockIdx.x;
  const int b = bh >> 4;
  const int h = bh & 15;
  const int vl = vlen[b];

  const float C1 = 0.18033688f;  // 0.125 * log2(e)
  const float C2 = 46.166241f;   // 32 * log2(e)
  const float mArg = (vl == 0) ? 0.0f : -12800.0f;

  bf16x8 qf[2][2];
#pragma unroll
  for (int a = 0; a < 2; a++) {
    const bf16* qb =
        qp + ((size_t)(bh * 2048 + qt * 128 + w * 32 + a * 16 + m16)) * 64;
    qf[a][0] = *(const bf16x8*)(qb + quad * 8);
    qf[a][1] = *(const bf16x8*)(qb + 32 + quad * 8);
  }

  float rsum[2][4] = {{0.f, 0.f, 0.f, 0.f}, {0.f, 0.f, 0.f, 0.f}};
  f32x4 o[2][4];
#pragma unroll
  for (int a = 0; a < 2; a++)
#pragma unroll
    for (int nt = 0; nt < 4; nt++) o[a][nt] = (f32x4){0.f, 0.f, 0.f, 0.f};

  const int ktEnd = (vl == 0) ? 32 : ((vl + 63) >> 6);

  for (int kt = 0; kt < ktEnd; kt++) {
    __syncthreads();  // prior readers done
#pragma unroll
    for (int p = 0; p < 2; p++) {
      int idx = p * 256 + t;  // 16B chunk; rows are 128B (64 bf16)
      int row = idx >> 3;
      int gc = (idx & 7) ^ (row & 7);  // XOR swizzle in global address
      gload_lds16(&Ks[idx * 8],
                  &kp[((size_t)(bh * 2048 + kt * 64 + row)) * 64 + gc * 8]);
      gload_lds16(&Vs[idx * 8],
                  &vt[((size_t)(bh * 64 + row)) * 2048 + kt * 64 + gc * 8]);
    }
    __syncthreads();  // DMA drained, staged data visible

    // ---- QK^T: 2 q-subtiles share each K fragment
    f32x4 s[2][4];
#pragma unroll
    for (int a = 0; a < 2; a++)
#pragma unroll
      for (int nt = 0; nt < 4; nt++) s[a][nt] = (f32x4){0.f, 0.f, 0.f, 0.f};
#pragma unroll
    for (int nt = 0; nt < 4; nt++) {
      int key = nt * 16 + m16;
#pragma unroll
      for (int ks = 0; ks < 2; ks++) {
        bf16x8 kf =
            *(const bf16x8*)&Ks[key * 64 + (((ks * 4 + quad) ^ sw) * 8)];
        s[0][nt] = MFMA16(qf[0][ks], kf, s[0][nt], 0, 0, 0);
        s[1][nt] = MFMA16(qf[1][ks], kf, s[1][nt], 0, 0, 0);
      }
    }

    // ---- p = exp2(dot*C1 - C2); masked -> 0 (or 1 when vl==0)
#pragma unroll
    for (int nt = 0; nt < 4; nt++) {
      bool masked = (kt * 64 + nt * 16 + m16) >= vl;
#pragma unroll
      for (int a = 0; a < 2; a++)
#pragma unroll
        for (int r = 0; r < 4; r++) {
          float arg = masked ? mArg : (s[a][nt][r] * C1 - C2);
          bf16 pb = (bf16)__builtin_amdgcn_exp2f(arg);
          rsum[a][r] += (float)pb;
          Ps[w * 2304 + (a * 16 + quad * 4 + r) * 72 + nt * 16 + m16] = pb;
        }
    }

    // ---- PV: 2 q-subtiles share each V fragment (per-wave DS is in-order)
#pragma unroll
    for (int ks = 0; ks < 2; ks++) {
      bf16x8 pf0 = *(const bf16x8*)&Ps[w * 2304 + m16 * 72 + ks * 32 + quad * 8];
      bf16x8 pf1 =
          *(const bf16x8*)&Ps[w * 2304 + (16 + m16) * 72 + ks * 32 + quad * 8];
#pragma unroll
      for (int nt = 0; nt < 4; nt++) {
        int dh = nt * 16 + m16;
        bf16x8 vf =
            *(const bf16x8*)&Vs[dh * 64 + (((ks * 4 + quad) ^ sw) * 8)];
        o[0][nt] = MFMA16(pf0, vf, o[0][nt], 0, 0, 0);
        o[1][nt] = MFMA16(pf1, vf, o[1][nt], 0, 0, 0);
      }
    }
  }

  // ---- deferred row-sum reduction across the 16 key-lanes
#pragma unroll
  for (int off = 1; off < 16; off <<= 1)
#pragma unroll
    for (int a = 0; a < 2; a++)
#pragma unroll
      for (int r = 0; r < 4; r++) rsum[a][r] += __shfl_xor(rsum[a][r], off);
#pragma unroll
  for (int a = 0; a < 2; a++)
#pragma unroll
    for (int r = 0; r < 4; r++) rsum[a][r] = 1.0f / rsum[a][r];

  // ---- epilogue: normalize, merge heads into ctx [B,S,D]
#pragma unroll
  for (int a = 0; a < 2; a++)
#pragma unroll
    for (int nt = 0; nt < 4; nt++) {
      int dh = nt * 16 + m16;
#pragma unroll
      for (int r = 0; r < 4; r++) {
        int srow = qt * 128 + w * 32 + a * 16 + quad * 4 + r;
        ctx[((size_t)(b * 2048 + srow)) * 1024 + h * 64 + dh] =
            (bf16)(o[a][nt][r] * rsum[a][r]);
      }
    }
}

// ---------------------------------------------------------------------------
extern "C" void kernel_launch(void* const* d_in, const int* in_sizes, int n_in,
                              void* d_out, int out_size, void* d_ws,
                              size_t ws_size, hipStream_t stream) {
  const float* key = (const float*)d_in[0];
  const float* query = (const float*)d_in[1];
  const float* value = (const float*)d_in[2];
  const int* vlen = (const int*)d_in[3];
  const float* Wk = (const float*)d_in[4];
  const float* Wq = (const float*)d_in[5];
  const float* Wv = (const float*)d_in[6];
  const float* Wo = (const float*)d_in[7];

  const size_t NE = (size_t)4 * 2048 * 1024;  // 8,388,608 elems per tensor
  const size_t WE = 1048576;                  // weight elems
  dim3 gb(256);

  const size_t needA = (4 * NE + 4 * WE) * sizeof(bf16);  // ~75.5 MB

  if (ws_size >= needA) {
    // Tier A: direct fp32-A QKV GEMM (no activation convert), vl-balanced
    // XCD swizzle, 128x64 output GEMM.
    bf16* qp = (bf16*)d_ws;
    bf16* kp = qp + NE;
    bf16* vt = kp + NE;
    bf16* ctx = vt + NE;
    bf16* wb = ctx + NE;

    cvt4<<<dim3(1024, 4), gb, 0, stream>>>(Wq, Wk, Wv, Wo, wb);
    gemm_qkv<<<dim3(8, 64, 3), gb, 0, stream>>>(query, key, value, wb, vlen,
                                                qp, kp, vt);
    attn<<<dim3(16, 64), gb, 0, stream>>>(qp, kp, vt, vlen, ctx);
    gemm_out<<<dim3(16, 64), gb, 0, stream>>>(ctx, wb + 3 * WE,
                                              (float*)d_out);
  } else {
    // Tier C: fp32 staging inside GEMM (R4 behavior).
    bf16* qp = (bf16*)d_ws;
    bf16* kp = qp + NE;
    bf16* vt = kp + NE;
    bf16* ctx = vt + NE;
    dim3 gg(8, 64);
    gemm_bt<1, 1><<<gg, gb, 0, stream>>>(query, Wq, qp, 1);
    gemm_bt<1, 1><<<gg, gb, 0, stream>>>(key, Wk, kp, 1);
    gemm_bt<1, 1><<<gg, gb, 0, stream>>>(value, Wv, vt, 2);
    attn<<<dim3(16, 64), gb, 0, stream>>>(qp, kp, vt, vlen, ctx);
    gemm_bt<0, 1><<<gg, gb, 0, stream>>>(ctx, Wo, d_out, 0);
  }
}